// Round 10
// baseline (159.667 us; speedup 1.0000x reference)
//
#include <hip/hip_runtime.h>
#include <hip/hip_bf16.h>

// BiMPM matching, B=32, L=128, H=200, NP=20.
// Input/output dtype (bf16 vs f32) detected at runtime from mask_p[0] bit
// pattern. Masked contexts kept ONLY as bf16 (exact: bf16 input x {0,1}
// mask). maxpool + cos GEMMs on bf16 MFMA, fragments loaded directly from
// global. R10 = exact R3 baseline (153.1us verified), with attmpm split
// into TWO half-launches (side as kernel arg) so the profiler's top-5
// surfaces prep and maxpool counters (never yet observed — attmpm's 5
// bench iterations always filled the table).
// 4 launches: prep, maxpool(+cos), attmpm(side=0), attmpm(side=1).
// Output: mv_p (32,128,105), mv_h same.

#define EPSF 1e-8f
#define NEGF -1e7f

constexpr int Bc = 32, Lc = 128, Hc = 200, NPc = 20, NCHc = 105;
constexpr int KP = 224;    // padded K (7 x 32)
constexpr size_t SLL = (size_t)Bc * Lc * Lc;   // 524288

// workspace layout (floats)
constexpr size_t OFF_COS    = 0;                   // [b][p][q]
constexpr size_t OFF_COST   = OFF_COS + SLL;       // [b][q][p]
constexpr size_t OFF_NORMP  = OFF_COST + SLL;
constexpr size_t OFF_NORMH  = OFF_NORMP + (size_t)Bc * Lc;
constexpr size_t OFF_LENP   = OFF_NORMH + (size_t)Bc * Lc;
constexpr size_t OFF_LENH   = OFF_LENP + Bc;
constexpr size_t OFF_LASTP  = OFF_LENH + Bc;
constexpr size_t OFF_LASTH  = OFF_LASTP + (size_t)Bc * Hc;
constexpr size_t OFF_NWP    = OFF_LASTH + (size_t)Bc * Hc;  // [b][np][l]
constexpr size_t OFF_NWH    = OFF_NWP + (size_t)Bc * NPc * Lc;
constexpr size_t OFF_MASKPF = OFF_NWH + (size_t)Bc * NPc * Lc;
constexpr size_t OFF_MASKHF = OFF_MASKPF + (size_t)Bc * Lc;
constexpr size_t OFF_FLAG   = OFF_MASKHF + (size_t)Bc * Lc;
constexpr size_t OFF_WT     = OFF_FLAG + 64;                // [h][64] squared weights
constexpr size_t OFF_RPMAX  = OFF_WT + (size_t)Hc * 64;     // [qi][b][np][p]
constexpr size_t OFF_RPSUM  = OFF_RPMAX + 2 * (size_t)Bc * NPc * Lc;
constexpr size_t OFF_CPMAX  = OFF_RPSUM + 2 * (size_t)Bc * NPc * Lc;  // [pi][b][np][q]
constexpr size_t OFF_CPSUM  = OFF_CPMAX + 2 * (size_t)Bc * NPc * Lc;
constexpr size_t OFF_CHB    = OFF_CPSUM + 2 * (size_t)Bc * NPc * Lc;  // bf16 [b][l][KP]
constexpr size_t OFF_CPB    = OFF_CHB + ((size_t)Bc * Lc * KP) / 2;   // bf16 [b][l][KP]
constexpr size_t OFF_W2K    = OFF_CPB + ((size_t)Bc * Lc * KP) / 2;   // f32 [np][KP]
constexpr size_t WS_FLOATS  = OFF_W2K + (size_t)NPc * KP;   // ~5.3M floats (~21 MB)

typedef __attribute__((ext_vector_type(8))) short short8v;
typedef __attribute__((ext_vector_type(4))) float float4v;
typedef __attribute__((ext_vector_type(2))) float float2v;

__device__ __forceinline__ float loadf(const void* p, size_t i, int isb) {
  if (isb) return __bfloat162float(((const __hip_bfloat16*)p)[i]);
  return ((const float*)p)[i];
}

__device__ __forceinline__ void storef(void* out, size_t i, float v, int isb) {
  if (isb) ((__hip_bfloat16*)out)[i] = __float2bfloat16(v);
  else ((float*)out)[i] = v;
}

__device__ __forceinline__ float s2f(unsigned short s) {
  union { unsigned u; float f; } c;
  c.u = ((unsigned)s) << 16;
  return c.f;
}

__device__ __forceinline__ short b2s(float f) {
  __hip_bfloat16 h = __float2bfloat16(f);
  union { __hip_bfloat16 b; short s; } u;
  u.b = h;
  return u.s;
}

// unpack bf16 lane, scale by w (f32), repack to bf16
__device__ __forceinline__ short8v weight8(short8v a, float4v w0, float4v w1) {
  short8v r;
#pragma unroll
  for (int e = 0; e < 8; e++) {
    float w = (e < 4) ? w0[e] : w1[e - 4];
    r[e] = b2s(s2f((unsigned short)a[e]) * w);
  }
  return r;
}

// ---------------- prep (+convert +lastlen), one launch -----------------------
__global__ __launch_bounds__(256) void prep_kernel(
    const void* __restrict__ cp_, const void* __restrict__ mp,
    const void* __restrict__ ch_, const void* __restrict__ mh,
    const void* __restrict__ wf, const void* __restrict__ wmp,
    const void* __restrict__ watt, const void* __restrict__ wma,
    float* __restrict__ ws) {
  int isb = (((const unsigned short*)mp)[0] == 0x3F80u) ? 1 : 0;
  int bid = blockIdx.x;
  int t = threadIdx.x;
  const int n0 = Bc * Lc;          // 4096
  if (bid < 2048) {
    int g = bid * 4 + (t >> 6);    // row index 0..8191
    int side = g >> 12;
    int bl = g & 4095;
    int b = bl >> 7, l = bl & 127;
    int lane = t & 63;
    const void* ctx = side ? ch_ : cp_;
    const void* maskin = side ? mh : mp;
    float mk = loadf(maskin, b * Lc + l, isb);
    size_t rowbase = ((size_t)b * Lc + l) * Hc;
    __hip_bfloat16* cb16 = (__hip_bfloat16*)(ws + (side ? OFF_CHB : OFF_CPB));
    size_t cb = ((size_t)b * Lc + l) * KP;

    float v[4];
    float ss = 0.f;
    for (int i = 0; i < 4; i++) {
      int h = lane + 64 * i;
      float x = 0.f;
      if (h < Hc) {
        x = loadf(ctx, rowbase + h, isb) * mk;
        cb16[cb + h] = __float2bfloat16(x);
      } else if (h < KP) {
        cb16[cb + h] = __float2bfloat16(0.f);
      }
      v[i] = x;
      ss += x * x;
    }
    for (int o = 32; o > 0; o >>= 1) ss += __shfl_xor(ss, o);
    if (lane == 0) ws[(side ? OFF_NORMH : OFF_NORMP) + b * Lc + l] = sqrtf(ss);

    float* nw = ws + (side ? OFF_NWH : OFF_NWP) + (size_t)b * NPc * Lc;
    for (int np_ = 0; np_ < NPc; np_++) {
      float s = 0.f;
      for (int i = 0; i < 4; i++) {
        int h = lane + 64 * i;
        if (h < Hc) {
          float w = loadf(wmp, (size_t)np_ * Hc + h, isb);
          float wx = w * v[i];
          s += wx * wx;
        }
      }
      for (int o = 32; o > 0; o >>= 1) s += __shfl_xor(s, o);
      if (lane == 0) nw[np_ * Lc + l] = sqrtf(s);
    }
    return;
  }
  int cb = bid - 2048;
  if (cb >= 100) {
    // lastlen: 16 blocks x 4 (side,b) pairs, one wave per pair
    int idx = (cb - 100) * 4 + (t >> 6);   // 0..63
    int side = idx >> 5, b = idx & 31;
    int lane = t & 63;
    const void* mask = side ? mh : mp;
    const void* ctx = side ? ch_ : cp_;
    float s = 0.f;
    for (int l = lane; l < Lc; l += 64) s += loadf(mask, b * Lc + l, isb);
    for (int o = 32; o > 0; o >>= 1) s += __shfl_xor(s, o);
    if (lane == 0) ws[(side ? OFF_LENH : OFF_LENP) + b] = s;
    int lidx = (int)(s + 0.5f) - 1;
    if (lidx < 0) lidx = 0;
    float mk = loadf(mask, b * Lc + lidx, isb);
    float* lastv = ws + (side ? OFF_LASTH : OFF_LASTP) + (size_t)b * Hc;
    for (int h = lane; h < Hc; h += 64)
      lastv[h] = loadf(ctx, ((size_t)b * Lc + lidx) * Hc + h, isb) * mk;
    return;
  }
  int g = cb * 256 + t;
  if (g == 0) ws[OFF_FLAG] = (float)isb;
  if (g < n0) {
    ws[OFF_MASKPF + g] = loadf(mp, g, isb);
  } else if (g < 2 * n0) {
    ws[OFF_MASKHF + (g - n0)] = loadf(mh, g - n0, isb);
  } else if (g < 2 * n0 + 64 * Hc) {
    // wT table, layout [h][64]: lane-coalesced channel reads
    int r = g - 2 * n0;
    int h = r >> 6, c = r & 63;
    float w = 1.0f;
    if (c < 20) w = loadf(wf, (size_t)c * Hc + h, isb);
    else if (c < 40) w = loadf(watt, (size_t)(c - 20) * Hc + h, isb);
    else if (c < 60) w = loadf(wma, (size_t)(c - 40) * Hc + h, isb);
    ws[OFF_WT + r] = w * w;
  } else if (g < 2 * n0 + 64 * Hc + NPc * KP) {
    int r = g - (2 * n0 + 64 * Hc);
    int np_ = r / KP, k = r % KP;
    float w = (k < Hc) ? loadf(wmp, (size_t)np_ * Hc + k, isb) : 0.f;
    ws[OFF_W2K + r] = w * w;
  }
}

// ---------------- maxpool + cos: 64x64x224 bf16-MFMA, no LDS, frag-direct ----
// grid (Bc, 4, NPc+1): b fastest -> all blocks of batch b on XCD b%8.
// blockIdx.z in [0,NPc) -> maxpool perspective; == NPc -> cos mode (exact).
__global__ __launch_bounds__(64, 3) void maxpool_kernel(float* __restrict__ ws) {
  int b = blockIdx.x;
  int s = blockIdx.y;            // 0..3
  int np_ = blockIdx.z;
  int pi = s >> 1, qi = s & 1;
  int cosmode = (np_ == NPc);
  int lane = threadIdx.x;        // 64, single wave
  int rsel = lane & 15, quad = lane >> 4;

  const short* Ab = (const short*)(ws + OFF_CPB)
                  + ((size_t)b * Lc + pi * 64 + rsel) * KP + quad * 8;
  const short* Bb = (const short*)(ws + OFF_CHB)
                  + ((size_t)b * Lc + qi * 64 + rsel) * KP + quad * 8;
  const float* w2k = ws + OFF_W2K + (size_t)(cosmode ? 0 : np_) * KP + quad * 8;

  float4v acc[4][4];
  float4v zf = {0.f, 0.f, 0.f, 0.f};
#pragma unroll
  for (int i = 0; i < 4; i++)
#pragma unroll
    for (int j = 0; j < 4; j++) acc[i][j] = zf;

#pragma unroll
  for (int st = 0; st < 7; st++) {
    int k0 = st * 32;
    short8v bf4[4], af[4];
#pragma unroll
    for (int t = 0; t < 4; t++)
      bf4[t] = *(const short8v*)(Bb + (size_t)t * 16 * KP + k0);
    if (cosmode) {
#pragma unroll
      for (int t = 0; t < 4; t++)
        af[t] = *(const short8v*)(Ab + (size_t)t * 16 * KP + k0);
    } else {
      float4v w0 = *(const float4v*)(w2k + k0);
      float4v w1 = *(const float4v*)(w2k + k0 + 4);
#pragma unroll
      for (int t = 0; t < 4; t++) {
        short8v ar = *(const short8v*)(Ab + (size_t)t * 16 * KP + k0);
        af[t] = weight8(ar, w0, w1);
      }
    }
#pragma unroll
    for (int i = 0; i < 4; i++)
#pragma unroll
      for (int j = 0; j < 4; j++)
        acc[i][j] = __builtin_amdgcn_mfma_f32_16x16x32_bf16(af[i], bf4[j], acc[i][j], 0, 0, 0);
  }

  if (cosmode) {
    const float* npn = ws + OFF_NORMP + b * Lc + pi * 64;
    const float* nhn = ws + OFF_NORMH + b * Lc + qi * 64;
    float nh4[4];
#pragma unroll
    for (int tj = 0; tj < 4; tj++) nh4[tj] = nhn[tj * 16 + rsel];
    float* cosp = ws + OFF_COS + (size_t)b * Lc * Lc;
    float* cost = ws + OFF_COST + (size_t)b * Lc * Lc;
#pragma unroll
    for (int ti = 0; ti < 4; ti++) {
#pragma unroll
      for (int r = 0; r < 4; r++) {
        int prow = pi * 64 + ti * 16 + quad * 4 + r;
        float npv = npn[ti * 16 + quad * 4 + r];
#pragma unroll
        for (int tj = 0; tj < 4; tj++) {
          int qcol = qi * 64 + tj * 16 + rsel;
          float v = acc[ti][tj][r] * __builtin_amdgcn_rcpf(fmaxf(npv * nh4[tj], EPSF));
          cosp[(size_t)prow * Lc + qcol] = v;
          cost[(size_t)qcol * Lc + prow] = v;
        }
      }
    }
    return;
  }

  // maxpool epilogue: v = acc / max(nwp*nwh, eps); masked max/mean partials
  const float* nwp = ws + OFF_NWP + ((size_t)b * NPc + np_) * Lc + pi * 64;
  const float* nwh = ws + OFF_NWH + ((size_t)b * NPc + np_) * Lc + qi * 64;
  const float* maskP = ws + OFF_MASKPF + b * Lc + pi * 64;
  const float* maskH = ws + OFF_MASKHF + b * Lc + qi * 64;
  float nhv[4], mhv[4], cmax[4], csum[4];
#pragma unroll
  for (int tj = 0; tj < 4; tj++) {
    int q = tj * 16 + rsel;
    nhv[tj] = nwh[q];
    mhv[tj] = maskH[q];
    cmax[tj] = NEGF;
    csum[tj] = 0.f;
  }
  size_t rbase = (((size_t)qi * Bc + b) * NPc + np_) * Lc + pi * 64;
  size_t cbase = (((size_t)pi * Bc + b) * NPc + np_) * Lc + qi * 64;
#pragma unroll
  for (int ti = 0; ti < 4; ti++) {
#pragma unroll
    for (int r = 0; r < 4; r++) {
      int p = ti * 16 + quad * 4 + r;
      float npv = nwp[p], mpv = maskP[p];
      float rm = NEGF, rs = 0.f;
#pragma unroll
      for (int tj = 0; tj < 4; tj++) {
        float v = acc[ti][tj][r] * __builtin_amdgcn_rcpf(fmaxf(npv * nhv[tj], EPSF));
        if (mhv[tj] > 0.f) rm = fmaxf(rm, v);
        rs += v * mhv[tj];
        if (mpv > 0.f) cmax[tj] = fmaxf(cmax[tj], v);
        csum[tj] += v * mpv;
      }
#pragma unroll
      for (int o = 1; o <= 8; o <<= 1) {
        rm = fmaxf(rm, __shfl_xor(rm, o));
        rs += __shfl_xor(rs, o);
      }
      if (rsel == 0) {
        ws[OFF_RPMAX + rbase + p] = rm;
        ws[OFF_RPSUM + rbase + p] = rs;
      }
    }
  }
#pragma unroll
  for (int tj = 0; tj < 4; tj++) {
#pragma unroll
    for (int o = 16; o <= 32; o <<= 1) {
      cmax[tj] = fmaxf(cmax[tj], __shfl_xor(cmax[tj], o));
      csum[tj] += __shfl_xor(csum[tj], o);
    }
  }
  if (quad == 0) {
#pragma unroll
    for (int tj = 0; tj < 4; tj++) {
      int q = tj * 16 + rsel;
      ws[OFF_CPMAX + cbase + q] = cmax[tj];
      ws[OFF_CPSUM + cbase + q] = csum[tj];
    }
  }
}

// ---------------- attmpm: att (8x-unrolled, f2-packed) + all channels --------
// grid (Bc, Lc/4), side passed as arg; launched twice (side 0 then 1) so the
// per-dispatch duration halves and prep/maxpool surface in the profiler.
// 256 threads = 4 waves; wave wv owns row r0+wv. Contexts read as bf16 (exact).
__global__ __launch_bounds__(256) void attmpm_kernel(float* __restrict__ ws,
                                                     void* __restrict__ out,
                                                     int side) {
  int b = blockIdx.x;
  int r0 = blockIdx.y * 4;
  int t = threadIdx.x;  // 256
  int isb = ws[OFF_FLAG] > 0.5f;
  const float* cosrows = ws + (side ? OFF_COST : OFF_COS) + ((size_t)b * Lc + r0) * Lc;
  const unsigned short* vsb = (const unsigned short*)(ws + (side ? OFF_CPB : OFF_CHB))
                            + (size_t)b * Lc * KP;
  const unsigned short* v1b = (const unsigned short*)(ws + (side ? OFF_CHB : OFF_CPB))
                            + ((size_t)b * Lc + r0) * KP;
  const float* vlast = ws + (side ? OFF_LASTP : OFF_LASTH) + (size_t)b * Hc;
  const float* maskRow = ws + (side ? OFF_MASKHF : OFF_MASKPF) + b * Lc;
  float lenOther = ws[(side ? OFF_LENP : OFF_LENH) + b];
  int lenO = (int)(lenOther + 0.5f);   // valid q = [0, lenO); cos==0 beyond
  size_t obase = (size_t)side * Bc * Lc * NCHc + ((size_t)b * Lc + r0) * NCHc;

  __shared__ float crowT[Lc][4];   // [q][row] packed for one b128 per q
  __shared__ float dens[4];
  __shared__ float v1s[4][Hc];
  __shared__ float v2l[Hc];
  __shared__ float am[4][Hc];
  __shared__ float ax[4][Hc];
  for (int i = t; i < 4 * Lc; i += 256) {
    int row = i >> 7, q = i & 127;
    crowT[q][row] = cosrows[(size_t)row * Lc + q];
  }
  for (int i = t; i < 4 * Hc; i += 256) {
    int row = i / Hc, h = i % Hc;
    v1s[row][h] = s2f(v1b[(size_t)row * KP + h]);
  }
  for (int h = t; h < Hc; h += 256) v2l[h] = vlast[h];
  __syncthreads();

  // per-row stats: wave wv handles row r0+wv -> denom + out channels 0,1
  int wv = t >> 6, lane = t & 63;
  {
    float x1 = crowT[lane][wv], x2 = crowT[lane + 64][wv];
    float sv = x1 + x2;               // x2 is exactly 0 beyond len
    float mv = fmaxf(x1, (lane + 64 < lenO) ? x2 : NEGF);  // len>=64: x1 always valid
    for (int o = 32; o > 0; o >>= 1) {
      sv += __shfl_xor(sv, o);
      mv = fmaxf(mv, __shfl_xor(mv, o));
    }
    if (lane == 0) {
      dens[wv] = sv;
      float mr = maskRow[r0 + wv];
      storef(out, obase + (size_t)wv * NCHc + 0, mr * mv, isb);
      storef(out, obase + (size_t)wv * NCHc + 1, mr * sv / fmaxf(mr * lenOther, EPSF), isb);
    }
  }
  __syncthreads();

  // attentive mean+max for the 4 rows -> LDS am/ax.
  // 8x-unrolled two-phase: 8 global loads in flight, then LDS, then pk math.
  if (t < Hc) {
    float2v s01 = {0.f, 0.f}, s23 = {0.f, 0.f};
    float2v m01 = {NEGF, NEGF}, m23 = {NEGF, NEGF};
    const unsigned short* vb = vsb + t;
    int q = 0;
    for (; q + 8 <= lenO; q += 8) {
      unsigned short raw[8];
#pragma unroll
      for (int j = 0; j < 8; j++) raw[j] = vb[(size_t)(q + j) * KP];
      float4 cc[8];
#pragma unroll
      for (int j = 0; j < 8; j++) cc[j] = *(const float4*)&crowT[q + j][0];
#pragma unroll
      for (int j = 0; j < 8; j++) {
        float pr = s2f(raw[j]);
        float2v pp = {pr, pr};
        float2v c01 = {cc[j].x, cc[j].y}, c23 = {cc[j].z, cc[j].w};
        float2v v01 = c01 * pp, v23 = c23 * pp;
        s01 += v01;
        s23 += v23;
        m01[0] = fmaxf(m01[0], v01[0]); m01[1] = fmaxf(m01[1], v01[1]);
        m23[0] = fmaxf(m23[0], v23[0]); m23[1] = fmaxf(m23[1], v23[1]);
      }
    }
    for (; q < lenO; q++) {
      float pr = s2f(vb[(size_t)q * KP]);
      float4 c4 = *(const float4*)&crowT[q][0];
      float2v pp = {pr, pr};
      float2v c01 = {c4.x, c4.y}, c23 = {c4.z, c4.w};
      float2v v01 = c01 * pp, v23 = c23 * pp;
      s01 += v01;
      s23 += v23;
      m01[0] = fmaxf(m01[0], v01[0]); m01[1] = fmaxf(m01[1], v01[1]);
      m23[0] = fmaxf(m23[0], v23[0]); m23[1] = fmaxf(m23[1], v23[1]);
    }
    am[0][t] = s01[0] / fmaxf(dens[0], EPSF);
    am[1][t] = s01[1] / fmaxf(dens[1], EPSF);
    am[2][t] = s23[0] / fmaxf(dens[2], EPSF);
    am[3][t] = s23[1] / fmaxf(dens[3], EPSF);
    ax[0][t] = maskRow[r0 + 0] * m01[0];
    ax[1][t] = maskRow[r0 + 1] * m01[1];
    ax[2][t] = maskRow[r0 + 2] * m23[0];
    ax[3][t] = maskRow[r0 + 3] * m23[1];
  }
  __syncthreads();

  // mpm channels: wave wv = row r0+wv, lane = channel
  int c = lane;
  int row = r0 + wv;
  size_t orow = obase + (size_t)wv * NCHc;

  // fused maxpool finalize: lanes 0..19 -> ch 23+c (max), 43+c (mean)
  if (c < NPc) {
    size_t PMX = side ? OFF_CPMAX : OFF_RPMAX;
    size_t PSM = side ? OFF_CPSUM : OFF_RPSUM;
    size_t i0 = (((size_t)0 * Bc + b) * NPc + c) * Lc + row;
    size_t i1 = (((size_t)1 * Bc + b) * NPc + c) * Lc + row;
    float m = fmaxf(ws[PMX + i0], ws[PMX + i1]);
    float sum = ws[PSM + i0] + ws[PSM + i1];
    float mk = maskRow[row];
    storef(out, orow + 23 + c, mk * m, isb);
    storef(out, orow + 43 + c, mk * sum / fmaxf(mk * lenOther, EPSF), isb);
  }

  int v2i = (c < 20) ? 0 : (c < 40) ? 1 : (c < 60) ? 2 : (c - 60);
  if (v2i > 2) v2i = 2;
  const float* y = (v2i == 0) ? v2l : (v2i == 1) ? am[wv] : ax[wv];
  const float* x = v1s[wv];
  const float* wtc = ws + OFF_WT + c;   // [h][64]: lane-coalesced dword loads
  float2v sd = {0.f, 0.f}, sa = {0.f, 0.f}, sb = {0.f, 0.f};
#pragma unroll 2
  for (int h4 = 0; h4 < Hc / 4; h4++) {
    float w0 = wtc[(size_t)(h4 * 4 + 0) * 64];
    float w1 = wtc[(size_t)(h4 * 4 + 1) * 64];
    float w2 = wtc[(size_t)(h4 * 4 + 2) * 64];
    float w3 = wtc[(size_t)(h4 * 4 + 3) * 64];
    float4 xv = *(const float4*)&x[h4 * 4];
    float4 yv = *(const float4*)&y[h4 * 4];
    float2v wq0 = {w0, w1}, wq1 = {w2, w3};
    float2v x0 = {xv.x, xv.y}, x1 = {xv.z, xv.w};
    float2v y0 = {yv.x, yv.y}, y1 = {yv.z, yv.w};
    float2v t0 = wq0 * x0;
    sd += t0 * y0; sa += t0 * x0; sb += wq0 * (y0 * y0);
    t0 = wq1 * x1;
    sd += t0 * y1; sa += t0 * x1; sb += wq1 * (y1 * y1);
  }
  float sdf = sd[0] + sd[1], saf = sa[0] + sa[1], sbf = sb[0] + sb[1];
  float mm = sdf / fmaxf(sqrtf(saf) * sqrtf(sbf), EPSF);
  int ch;
  if (c < 20) ch = 3 + c;
  else if (c < 40) ch = 64 + (c - 20);
  else if (c < 60) ch = 85 + (c - 40);
  else if (c == 60) ch = 2;
  else if (c == 61) ch = 63;
  else if (c == 62) ch = 84;
  else ch = -1;
  if (ch >= 0) storef(out, orow + ch, mm, isb);
}

extern "C" void kernel_launch(void* const* d_in, const int* in_sizes, int n_in,
                              void* d_out, int out_size, void* d_ws, size_t ws_size,
                              hipStream_t stream) {
  const void* ctx_p = d_in[0];
  const void* mask_p = d_in[1];
  const void* ctx_h = d_in[2];
  const void* mask_h = d_in[3];
  const void* w_full = d_in[4];
  const void* w_mp = d_in[5];
  const void* w_att = d_in[6];
  const void* w_maxatt = d_in[7];
  float* ws = (float*)d_ws;

  prep_kernel<<<2164, 256, 0, stream>>>(ctx_p, mask_p, ctx_h, mask_h,
                                        w_full, w_mp, w_att, w_maxatt, ws);
  maxpool_kernel<<<dim3(Bc, 4, NPc + 1), 64, 0, stream>>>(ws);
  attmpm_kernel<<<dim3(Bc, Lc / 4), 256, 0, stream>>>(ws, d_out, 0);
  attmpm_kernel<<<dim3(Bc, Lc / 4), 256, 0, stream>>>(ws, d_out, 1);
}

// Round 11
// 152.646 us; speedup vs baseline: 1.0460x; 1.0460x over previous
//
#include <hip/hip_runtime.h>
#include <hip/hip_bf16.h>

// BiMPM matching, B=32, L=128, H=200, NP=20.
// Input/output dtype (bf16 vs f32) detected at runtime from mask_p[0] bit
// pattern. Masked contexts kept ONLY as bf16 (exact: bf16 input x {0,1}
// mask). maxpool + cos GEMMs on bf16 MFMA, fragments loaded directly from
// global. 3 launches: prep(+convert+lastlen), maxpool(+cos), attmpm.
// R11 = exact R3 baseline (153.1us verified) + ONE isolated change:
//   maxpool grid z: cos-mode moved from z==NPc (dispatched LAST -> serial
//   tail of the most expensive blocks) to z==0 (dispatched FIRST; np-blocks
//   backfill behind). np_ = z-1 for z>=1. No numeric change.
// Measured decomposition (R10): ~41us harness ws-fill (fixed) + attmpm 47
// + maxpool ~40 + prep ~20 + gaps ~5.
// Output: mv_p (32,128,105), mv_h same.

#define EPSF 1e-8f
#define NEGF -1e7f

constexpr int Bc = 32, Lc = 128, Hc = 200, NPc = 20, NCHc = 105;
constexpr int KP = 224;    // padded K (7 x 32)
constexpr size_t SLL = (size_t)Bc * Lc * Lc;   // 524288

// workspace layout (floats)
constexpr size_t OFF_COS    = 0;                   // [b][p][q]
constexpr size_t OFF_COST   = OFF_COS + SLL;       // [b][q][p]
constexpr size_t OFF_NORMP  = OFF_COST + SLL;
constexpr size_t OFF_NORMH  = OFF_NORMP + (size_t)Bc * Lc;
constexpr size_t OFF_LENP   = OFF_NORMH + (size_t)Bc * Lc;
constexpr size_t OFF_LENH   = OFF_LENP + Bc;
constexpr size_t OFF_LASTP  = OFF_LENH + Bc;
constexpr size_t OFF_LASTH  = OFF_LASTP + (size_t)Bc * Hc;
constexpr size_t OFF_NWP    = OFF_LASTH + (size_t)Bc * Hc;  // [b][np][l]
constexpr size_t OFF_NWH    = OFF_NWP + (size_t)Bc * NPc * Lc;
constexpr size_t OFF_MASKPF = OFF_NWH + (size_t)Bc * NPc * Lc;
constexpr size_t OFF_MASKHF = OFF_MASKPF + (size_t)Bc * Lc;
constexpr size_t OFF_FLAG   = OFF_MASKHF + (size_t)Bc * Lc;
constexpr size_t OFF_WT     = OFF_FLAG + 64;                // [h][64] squared weights
constexpr size_t OFF_RPMAX  = OFF_WT + (size_t)Hc * 64;     // [qi][b][np][p]
constexpr size_t OFF_RPSUM  = OFF_RPMAX + 2 * (size_t)Bc * NPc * Lc;
constexpr size_t OFF_CPMAX  = OFF_RPSUM + 2 * (size_t)Bc * NPc * Lc;  // [pi][b][np][q]
constexpr size_t OFF_CPSUM  = OFF_CPMAX + 2 * (size_t)Bc * NPc * Lc;
constexpr size_t OFF_CHB    = OFF_CPSUM + 2 * (size_t)Bc * NPc * Lc;  // bf16 [b][l][KP]
constexpr size_t OFF_CPB    = OFF_CHB + ((size_t)Bc * Lc * KP) / 2;   // bf16 [b][l][KP]
constexpr size_t OFF_W2K    = OFF_CPB + ((size_t)Bc * Lc * KP) / 2;   // f32 [np][KP]
constexpr size_t WS_FLOATS  = OFF_W2K + (size_t)NPc * KP;   // ~5.3M floats (~21 MB)

typedef __attribute__((ext_vector_type(8))) short short8v;
typedef __attribute__((ext_vector_type(4))) float float4v;
typedef __attribute__((ext_vector_type(2))) float float2v;

__device__ __forceinline__ float loadf(const void* p, size_t i, int isb) {
  if (isb) return __bfloat162float(((const __hip_bfloat16*)p)[i]);
  return ((const float*)p)[i];
}

__device__ __forceinline__ void storef(void* out, size_t i, float v, int isb) {
  if (isb) ((__hip_bfloat16*)out)[i] = __float2bfloat16(v);
  else ((float*)out)[i] = v;
}

__device__ __forceinline__ float s2f(unsigned short s) {
  union { unsigned u; float f; } c;
  c.u = ((unsigned)s) << 16;
  return c.f;
}

__device__ __forceinline__ short b2s(float f) {
  __hip_bfloat16 h = __float2bfloat16(f);
  union { __hip_bfloat16 b; short s; } u;
  u.b = h;
  return u.s;
}

// unpack bf16 lane, scale by w (f32), repack to bf16
__device__ __forceinline__ short8v weight8(short8v a, float4v w0, float4v w1) {
  short8v r;
#pragma unroll
  for (int e = 0; e < 8; e++) {
    float w = (e < 4) ? w0[e] : w1[e - 4];
    r[e] = b2s(s2f((unsigned short)a[e]) * w);
  }
  return r;
}

// ---------------- prep (+convert +lastlen), one launch -----------------------
__global__ __launch_bounds__(256) void prep_kernel(
    const void* __restrict__ cp_, const void* __restrict__ mp,
    const void* __restrict__ ch_, const void* __restrict__ mh,
    const void* __restrict__ wf, const void* __restrict__ wmp,
    const void* __restrict__ watt, const void* __restrict__ wma,
    float* __restrict__ ws) {
  int isb = (((const unsigned short*)mp)[0] == 0x3F80u) ? 1 : 0;
  int bid = blockIdx.x;
  int t = threadIdx.x;
  const int n0 = Bc * Lc;          // 4096
  if (bid < 2048) {
    int g = bid * 4 + (t >> 6);    // row index 0..8191
    int side = g >> 12;
    int bl = g & 4095;
    int b = bl >> 7, l = bl & 127;
    int lane = t & 63;
    const void* ctx = side ? ch_ : cp_;
    const void* maskin = side ? mh : mp;
    float mk = loadf(maskin, b * Lc + l, isb);
    size_t rowbase = ((size_t)b * Lc + l) * Hc;
    __hip_bfloat16* cb16 = (__hip_bfloat16*)(ws + (side ? OFF_CHB : OFF_CPB));
    size_t cb = ((size_t)b * Lc + l) * KP;

    float v[4];
    float ss = 0.f;
    for (int i = 0; i < 4; i++) {
      int h = lane + 64 * i;
      float x = 0.f;
      if (h < Hc) {
        x = loadf(ctx, rowbase + h, isb) * mk;
        cb16[cb + h] = __float2bfloat16(x);
      } else if (h < KP) {
        cb16[cb + h] = __float2bfloat16(0.f);
      }
      v[i] = x;
      ss += x * x;
    }
    for (int o = 32; o > 0; o >>= 1) ss += __shfl_xor(ss, o);
    if (lane == 0) ws[(side ? OFF_NORMH : OFF_NORMP) + b * Lc + l] = sqrtf(ss);

    float* nw = ws + (side ? OFF_NWH : OFF_NWP) + (size_t)b * NPc * Lc;
    for (int np_ = 0; np_ < NPc; np_++) {
      float s = 0.f;
      for (int i = 0; i < 4; i++) {
        int h = lane + 64 * i;
        if (h < Hc) {
          float w = loadf(wmp, (size_t)np_ * Hc + h, isb);
          float wx = w * v[i];
          s += wx * wx;
        }
      }
      for (int o = 32; o > 0; o >>= 1) s += __shfl_xor(s, o);
      if (lane == 0) nw[np_ * Lc + l] = sqrtf(s);
    }
    return;
  }
  int cb = bid - 2048;
  if (cb >= 100) {
    // lastlen: 16 blocks x 4 (side,b) pairs, one wave per pair
    int idx = (cb - 100) * 4 + (t >> 6);   // 0..63
    int side = idx >> 5, b = idx & 31;
    int lane = t & 63;
    const void* mask = side ? mh : mp;
    const void* ctx = side ? ch_ : cp_;
    float s = 0.f;
    for (int l = lane; l < Lc; l += 64) s += loadf(mask, b * Lc + l, isb);
    for (int o = 32; o > 0; o >>= 1) s += __shfl_xor(s, o);
    if (lane == 0) ws[(side ? OFF_LENH : OFF_LENP) + b] = s;
    int lidx = (int)(s + 0.5f) - 1;
    if (lidx < 0) lidx = 0;
    float mk = loadf(mask, b * Lc + lidx, isb);
    float* lastv = ws + (side ? OFF_LASTH : OFF_LASTP) + (size_t)b * Hc;
    for (int h = lane; h < Hc; h += 64)
      lastv[h] = loadf(ctx, ((size_t)b * Lc + lidx) * Hc + h, isb) * mk;
    return;
  }
  int g = cb * 256 + t;
  if (g == 0) ws[OFF_FLAG] = (float)isb;
  if (g < n0) {
    ws[OFF_MASKPF + g] = loadf(mp, g, isb);
  } else if (g < 2 * n0) {
    ws[OFF_MASKHF + (g - n0)] = loadf(mh, g - n0, isb);
  } else if (g < 2 * n0 + 64 * Hc) {
    // wT table, layout [h][64]: lane-coalesced channel reads
    int r = g - 2 * n0;
    int h = r >> 6, c = r & 63;
    float w = 1.0f;
    if (c < 20) w = loadf(wf, (size_t)c * Hc + h, isb);
    else if (c < 40) w = loadf(watt, (size_t)(c - 20) * Hc + h, isb);
    else if (c < 60) w = loadf(wma, (size_t)(c - 40) * Hc + h, isb);
    ws[OFF_WT + r] = w * w;
  } else if (g < 2 * n0 + 64 * Hc + NPc * KP) {
    int r = g - (2 * n0 + 64 * Hc);
    int np_ = r / KP, k = r % KP;
    float w = (k < Hc) ? loadf(wmp, (size_t)np_ * Hc + k, isb) : 0.f;
    ws[OFF_W2K + r] = w * w;
  }
}

// ---------------- maxpool + cos: 64x64x224 bf16-MFMA, no LDS, frag-direct ----
// grid (Bc, 4, NPc+1): b fastest -> all blocks of batch b on XCD b%8.
// z==0 -> cos mode (dispatched FIRST: kills the expensive-block tail);
// z>=1 -> maxpool perspective np_ = z-1.
__global__ __launch_bounds__(64, 3) void maxpool_kernel(float* __restrict__ ws) {
  int b = blockIdx.x;
  int s = blockIdx.y;            // 0..3
  int z = blockIdx.z;            // 0..20
  int pi = s >> 1, qi = s & 1;
  int cosmode = (z == 0);
  int np_ = cosmode ? 0 : z - 1;
  int lane = threadIdx.x;        // 64, single wave
  int rsel = lane & 15, quad = lane >> 4;

  const short* Ab = (const short*)(ws + OFF_CPB)
                  + ((size_t)b * Lc + pi * 64 + rsel) * KP + quad * 8;
  const short* Bb = (const short*)(ws + OFF_CHB)
                  + ((size_t)b * Lc + qi * 64 + rsel) * KP + quad * 8;
  const float* w2k = ws + OFF_W2K + (size_t)np_ * KP + quad * 8;

  float4v acc[4][4];
  float4v zf = {0.f, 0.f, 0.f, 0.f};
#pragma unroll
  for (int i = 0; i < 4; i++)
#pragma unroll
    for (int j = 0; j < 4; j++) acc[i][j] = zf;

#pragma unroll
  for (int st = 0; st < 7; st++) {
    int k0 = st * 32;
    short8v bf4[4], af[4];
#pragma unroll
    for (int t = 0; t < 4; t++)
      bf4[t] = *(const short8v*)(Bb + (size_t)t * 16 * KP + k0);
    if (cosmode) {
#pragma unroll
      for (int t = 0; t < 4; t++)
        af[t] = *(const short8v*)(Ab + (size_t)t * 16 * KP + k0);
    } else {
      float4v w0 = *(const float4v*)(w2k + k0);
      float4v w1 = *(const float4v*)(w2k + k0 + 4);
#pragma unroll
      for (int t = 0; t < 4; t++) {
        short8v ar = *(const short8v*)(Ab + (size_t)t * 16 * KP + k0);
        af[t] = weight8(ar, w0, w1);
      }
    }
#pragma unroll
    for (int i = 0; i < 4; i++)
#pragma unroll
      for (int j = 0; j < 4; j++)
        acc[i][j] = __builtin_amdgcn_mfma_f32_16x16x32_bf16(af[i], bf4[j], acc[i][j], 0, 0, 0);
  }

  if (cosmode) {
    const float* npn = ws + OFF_NORMP + b * Lc + pi * 64;
    const float* nhn = ws + OFF_NORMH + b * Lc + qi * 64;
    float nh4[4];
#pragma unroll
    for (int tj = 0; tj < 4; tj++) nh4[tj] = nhn[tj * 16 + rsel];
    float* cosp = ws + OFF_COS + (size_t)b * Lc * Lc;
    float* cost = ws + OFF_COST + (size_t)b * Lc * Lc;
#pragma unroll
    for (int ti = 0; ti < 4; ti++) {
#pragma unroll
      for (int r = 0; r < 4; r++) {
        int prow = pi * 64 + ti * 16 + quad * 4 + r;
        float npv = npn[ti * 16 + quad * 4 + r];
#pragma unroll
        for (int tj = 0; tj < 4; tj++) {
          int qcol = qi * 64 + tj * 16 + rsel;
          float v = acc[ti][tj][r] * __builtin_amdgcn_rcpf(fmaxf(npv * nh4[tj], EPSF));
          cosp[(size_t)prow * Lc + qcol] = v;
          cost[(size_t)qcol * Lc + prow] = v;
        }
      }
    }
    return;
  }

  // maxpool epilogue: v = acc / max(nwp*nwh, eps); masked max/mean partials
  const float* nwp = ws + OFF_NWP + ((size_t)b * NPc + np_) * Lc + pi * 64;
  const float* nwh = ws + OFF_NWH + ((size_t)b * NPc + np_) * Lc + qi * 64;
  const float* maskP = ws + OFF_MASKPF + b * Lc + pi * 64;
  const float* maskH = ws + OFF_MASKHF + b * Lc + qi * 64;
  float nhv[4], mhv[4], cmax[4], csum[4];
#pragma unroll
  for (int tj = 0; tj < 4; tj++) {
    int q = tj * 16 + rsel;
    nhv[tj] = nwh[q];
    mhv[tj] = maskH[q];
    cmax[tj] = NEGF;
    csum[tj] = 0.f;
  }
  size_t rbase = (((size_t)qi * Bc + b) * NPc + np_) * Lc + pi * 64;
  size_t cbase = (((size_t)pi * Bc + b) * NPc + np_) * Lc + qi * 64;
#pragma unroll
  for (int ti = 0; ti < 4; ti++) {
#pragma unroll
    for (int r = 0; r < 4; r++) {
      int p = ti * 16 + quad * 4 + r;
      float npv = nwp[p], mpv = maskP[p];
      float rm = NEGF, rs = 0.f;
#pragma unroll
      for (int tj = 0; tj < 4; tj++) {
        float v = acc[ti][tj][r] * __builtin_amdgcn_rcpf(fmaxf(npv * nhv[tj], EPSF));
        if (mhv[tj] > 0.f) rm = fmaxf(rm, v);
        rs += v * mhv[tj];
        if (mpv > 0.f) cmax[tj] = fmaxf(cmax[tj], v);
        csum[tj] += v * mpv;
      }
#pragma unroll
      for (int o = 1; o <= 8; o <<= 1) {
        rm = fmaxf(rm, __shfl_xor(rm, o));
        rs += __shfl_xor(rs, o);
      }
      if (rsel == 0) {
        ws[OFF_RPMAX + rbase + p] = rm;
        ws[OFF_RPSUM + rbase + p] = rs;
      }
    }
  }
#pragma unroll
  for (int tj = 0; tj < 4; tj++) {
#pragma unroll
    for (int o = 16; o <= 32; o <<= 1) {
      cmax[tj] = fmaxf(cmax[tj], __shfl_xor(cmax[tj], o));
      csum[tj] += __shfl_xor(csum[tj], o);
    }
  }
  if (quad == 0) {
#pragma unroll
    for (int tj = 0; tj < 4; tj++) {
      int q = tj * 16 + rsel;
      ws[OFF_CPMAX + cbase + q] = cmax[tj];
      ws[OFF_CPSUM + cbase + q] = csum[tj];
    }
  }
}

// ---------------- attmpm: att (8x-unrolled, f2-packed) + all channels --------
// grid (Bc, Lc/4, 2): b fastest -> all blocks of batch b on XCD b%8.
// 256 threads = 4 waves; wave wv owns row r0+wv. Contexts read as bf16 (exact).
__global__ __launch_bounds__(256) void attmpm_kernel(float* __restrict__ ws,
                                                     void* __restrict__ out) {
  int b = blockIdx.x;
  int r0 = blockIdx.y * 4;
  int side = blockIdx.z;
  int t = threadIdx.x;  // 256
  int isb = ws[OFF_FLAG] > 0.5f;
  const float* cosrows = ws + (side ? OFF_COST : OFF_COS) + ((size_t)b * Lc + r0) * Lc;
  const unsigned short* vsb = (const unsigned short*)(ws + (side ? OFF_CPB : OFF_CHB))
                            + (size_t)b * Lc * KP;
  const unsigned short* v1b = (const unsigned short*)(ws + (side ? OFF_CHB : OFF_CPB))
                            + ((size_t)b * Lc + r0) * KP;
  const float* vlast = ws + (side ? OFF_LASTP : OFF_LASTH) + (size_t)b * Hc;
  const float* maskRow = ws + (side ? OFF_MASKHF : OFF_MASKPF) + b * Lc;
  float lenOther = ws[(side ? OFF_LENP : OFF_LENH) + b];
  int lenO = (int)(lenOther + 0.5f);   // valid q = [0, lenO); cos==0 beyond
  size_t obase = (size_t)side * Bc * Lc * NCHc + ((size_t)b * Lc + r0) * NCHc;

  __shared__ float crowT[Lc][4];   // [q][row] packed for one b128 per q
  __shared__ float dens[4];
  __shared__ float v1s[4][Hc];
  __shared__ float v2l[Hc];
  __shared__ float am[4][Hc];
  __shared__ float ax[4][Hc];
  for (int i = t; i < 4 * Lc; i += 256) {
    int row = i >> 7, q = i & 127;
    crowT[q][row] = cosrows[(size_t)row * Lc + q];
  }
  for (int i = t; i < 4 * Hc; i += 256) {
    int row = i / Hc, h = i % Hc;
    v1s[row][h] = s2f(v1b[(size_t)row * KP + h]);
  }
  for (int h = t; h < Hc; h += 256) v2l[h] = vlast[h];
  __syncthreads();

  // per-row stats: wave wv handles row r0+wv -> denom + out channels 0,1
  int wv = t >> 6, lane = t & 63;
  {
    float x1 = crowT[lane][wv], x2 = crowT[lane + 64][wv];
    float sv = x1 + x2;               // x2 is exactly 0 beyond len
    float mv = fmaxf(x1, (lane + 64 < lenO) ? x2 : NEGF);  // len>=64: x1 always valid
    for (int o = 32; o > 0; o >>= 1) {
      sv += __shfl_xor(sv, o);
      mv = fmaxf(mv, __shfl_xor(mv, o));
    }
    if (lane == 0) {
      dens[wv] = sv;
      float mr = maskRow[r0 + wv];
      storef(out, obase + (size_t)wv * NCHc + 0, mr * mv, isb);
      storef(out, obase + (size_t)wv * NCHc + 1, mr * sv / fmaxf(mr * lenOther, EPSF), isb);
    }
  }
  __syncthreads();

  // attentive mean+max for the 4 rows -> LDS am/ax.
  // 8x-unrolled two-phase: 8 global loads in flight, then LDS, then pk math.
  if (t < Hc) {
    float2v s01 = {0.f, 0.f}, s23 = {0.f, 0.f};
    float2v m01 = {NEGF, NEGF}, m23 = {NEGF, NEGF};
    const unsigned short* vb = vsb + t;
    int q = 0;
    for (; q + 8 <= lenO; q += 8) {
      unsigned short raw[8];
#pragma unroll
      for (int j = 0; j < 8; j++) raw[j] = vb[(size_t)(q + j) * KP];
      float4 cc[8];
#pragma unroll
      for (int j = 0; j < 8; j++) cc[j] = *(const float4*)&crowT[q + j][0];
#pragma unroll
      for (int j = 0; j < 8; j++) {
        float pr = s2f(raw[j]);
        float2v pp = {pr, pr};
        float2v c01 = {cc[j].x, cc[j].y}, c23 = {cc[j].z, cc[j].w};
        float2v v01 = c01 * pp, v23 = c23 * pp;
        s01 += v01;
        s23 += v23;
        m01[0] = fmaxf(m01[0], v01[0]); m01[1] = fmaxf(m01[1], v01[1]);
        m23[0] = fmaxf(m23[0], v23[0]); m23[1] = fmaxf(m23[1], v23[1]);
      }
    }
    for (; q < lenO; q++) {
      float pr = s2f(vb[(size_t)q * KP]);
      float4 c4 = *(const float4*)&crowT[q][0];
      float2v pp = {pr, pr};
      float2v c01 = {c4.x, c4.y}, c23 = {c4.z, c4.w};
      float2v v01 = c01 * pp, v23 = c23 * pp;
      s01 += v01;
      s23 += v23;
      m01[0] = fmaxf(m01[0], v01[0]); m01[1] = fmaxf(m01[1], v01[1]);
      m23[0] = fmaxf(m23[0], v23[0]); m23[1] = fmaxf(m23[1], v23[1]);
    }
    am[0][t] = s01[0] / fmaxf(dens[0], EPSF);
    am[1][t] = s01[1] / fmaxf(dens[1], EPSF);
    am[2][t] = s23[0] / fmaxf(dens[2], EPSF);
    am[3][t] = s23[1] / fmaxf(dens[3], EPSF);
    ax[0][t] = maskRow[r0 + 0] * m01[0];
    ax[1][t] = maskRow[r0 + 1] * m01[1];
    ax[2][t] = maskRow[r0 + 2] * m23[0];
    ax[3][t] = maskRow[r0 + 3] * m23[1];
  }
  __syncthreads();

  // mpm channels: wave wv = row r0+wv, lane = channel
  int c = lane;
  int row = r0 + wv;
  size_t orow = obase + (size_t)wv * NCHc;

  // fused maxpool finalize: lanes 0..19 -> ch 23+c (max), 43+c (mean)
  if (c < NPc) {
    size_t PMX = side ? OFF_CPMAX : OFF_RPMAX;
    size_t PSM = side ? OFF_CPSUM : OFF_RPSUM;
    size_t i0 = (((size_t)0 * Bc + b) * NPc + c) * Lc + row;
    size_t i1 = (((size_t)1 * Bc + b) * NPc + c) * Lc + row;
    float m = fmaxf(ws[PMX + i0], ws[PMX + i1]);
    float sum = ws[PSM + i0] + ws[PSM + i1];
    float mk = maskRow[row];
    storef(out, orow + 23 + c, mk * m, isb);
    storef(out, orow + 43 + c, mk * sum / fmaxf(mk * lenOther, EPSF), isb);
  }

  int v2i = (c < 20) ? 0 : (c < 40) ? 1 : (c < 60) ? 2 : (c - 60);
  if (v2i > 2) v2i = 2;
  const float* y = (v2i == 0) ? v2l : (v2i == 1) ? am[wv] : ax[wv];
  const float* x = v1s[wv];
  const float* wtc = ws + OFF_WT + c;   // [h][64]: lane-coalesced dword loads
  float2v sd = {0.f, 0.f}, sa = {0.f, 0.f}, sb = {0.f, 0.f};
#pragma unroll 2
  for (int h4 = 0; h4 < Hc / 4; h4++) {
    float w0 = wtc[(size_t)(h4 * 4 + 0) * 64];
    float w1 = wtc[(size_t)(h4 * 4 + 1) * 64];
    float w2 = wtc[(size_t)(h4 * 4 + 2) * 64];
    float w3 = wtc[(size_t)(h4 * 4 + 3) * 64];
    float4 xv = *(const float4*)&x[h4 * 4];
    float4 yv = *(const float4*)&y[h4 * 4];
    float2v wq0 = {w0, w1}, wq1 = {w2, w3};
    float2v x0 = {xv.x, xv.y}, x1 = {xv.z, xv.w};
    float2v y0 = {yv.x, yv.y}, y1 = {yv.z, yv.w};
    float2v t0 = wq0 * x0;
    sd += t0 * y0; sa += t0 * x0; sb += wq0 * (y0 * y0);
    t0 = wq1 * x1;
    sd += t0 * y1; sa += t0 * x1; sb += wq1 * (y1 * y1);
  }
  float sdf = sd[0] + sd[1], saf = sa[0] + sa[1], sbf = sb[0] + sb[1];
  float mm = sdf / fmaxf(sqrtf(saf) * sqrtf(sbf), EPSF);
  int ch;
  if (c < 20) ch = 3 + c;
  else if (c < 40) ch = 64 + (c - 20);
  else if (c < 60) ch = 85 + (c - 40);
  else if (c == 60) ch = 2;
  else if (c == 61) ch = 63;
  else if (c == 62) ch = 84;
  else ch = -1;
  if (ch >= 0) storef(out, orow + ch, mm, isb);
}

extern "C" void kernel_launch(void* const* d_in, const int* in_sizes, int n_in,
                              void* d_out, int out_size, void* d_ws, size_t ws_size,
                              hipStream_t stream) {
  const void* ctx_p = d_in[0];
  const void* mask_p = d_in[1];
  const void* ctx_h = d_in[2];
  const void* mask_h = d_in[3];
  const void* w_full = d_in[4];
  const void* w_mp = d_in[5];
  const void* w_att = d_in[6];
  const void* w_maxatt = d_in[7];
  float* ws = (float*)d_ws;

  prep_kernel<<<2164, 256, 0, stream>>>(ctx_p, mask_p, ctx_h, mask_h,
                                        w_full, w_mp, w_att, w_maxatt, ws);
  maxpool_kernel<<<dim3(Bc, 4, NPc + 1), 64, 0, stream>>>(ws);
  attmpm_kernel<<<dim3(Bc, Lc / 4, 2), 256, 0, stream>>>(ws, d_out);
}